// Round 2
// baseline (330.543 us; speedup 1.0000x reference)
//
#include <hip/hip_runtime.h>

#define NUM_BINS 1025
#define NBLK 2048
#define BLOCK 256
#define NCOPY 4   // one private histogram per wave

// Stage 1: per-WAVE signed LDS histograms (+origin, -pre), summed and
// flushed to d_ws as partial[block][NUM_BINS].
__global__ __launch_bounds__(BLOCK) void hist_kernel(
    const float* __restrict__ od, const int* __restrict__ om,
    const float* __restrict__ pd, const int* __restrict__ nm,
    float* __restrict__ partial, int n)
{
    __shared__ float lh[NCOPY][NUM_BINS];
    const int tid  = threadIdx.x;
    const int wave = tid >> 6;
    float* h = lh[wave];

    float* flat = &lh[0][0];
    for (int b = tid; b < NCOPY * NUM_BINS; b += BLOCK) flat[b] = 0.0f;
    __syncthreads();

    const int n4 = n >> 2;
    const float4* od4 = (const float4*)od;
    const int4*   om4 = (const int4*)om;
    const float4* pd4 = (const float4*)pd;
    const int4*   nm4 = (const int4*)nm;

    const int stride = gridDim.x * BLOCK;
    int i = blockIdx.x * BLOCK + tid;
    if (i < n4) {
        float4 d = od4[i]; int4 m = om4[i];
        float4 e = pd4[i]; int4 q = nm4[i];
        for (;;) {
            const int j = i + stride;
            const bool more = j < n4;
            float4 d2, e2; int4 m2, q2;
            if (more) { d2 = od4[j]; m2 = om4[j]; e2 = pd4[j]; q2 = nm4[j]; }
            // native ds_add_f32 (no CAS loop)
            unsafeAtomicAdd(&h[m.x], d.x);
            unsafeAtomicAdd(&h[m.y], d.y);
            unsafeAtomicAdd(&h[m.z], d.z);
            unsafeAtomicAdd(&h[m.w], d.w);
            unsafeAtomicAdd(&h[q.x], -e.x);
            unsafeAtomicAdd(&h[q.y], -e.y);
            unsafeAtomicAdd(&h[q.z], -e.z);
            unsafeAtomicAdd(&h[q.w], -e.w);
            if (!more) break;
            d = d2; m = m2; e = e2; q = q2; i = j;
        }
    }
    // scalar tail (n % 4) — empty for 4096x4096
    if (blockIdx.x == 0 && tid == 0) {
        for (int k = n4 << 2; k < n; ++k) {
            unsafeAtomicAdd(&h[om[k]], od[k]);
            unsafeAtomicAdd(&h[nm[k]], -pd[k]);
        }
    }
    __syncthreads();

    float* row = partial + (size_t)blockIdx.x * NUM_BINS;
    for (int b = tid; b < NUM_BINS; b += BLOCK)
        row[b] = lh[0][b] + lh[1][b] + lh[2][b] + lh[3][b];
}

// Stage 2: 64 consecutive bins per block (coalesced lane reads); 4 waves
// split the block-index range; LDS combine -> abs -> wave reduce -> atomic.
__global__ __launch_bounds__(256) void reduce_kernel(
    const float* __restrict__ partial, float* __restrict__ out, int nblk)
{
    const int lane = threadIdx.x & 63;
    const int wave = threadIdx.x >> 6;
    const int bin  = blockIdx.x * 64 + lane;

    float s = 0.0f;
    if (bin < NUM_BINS)
        for (int k = wave; k < nblk; k += 4)
            s += partial[(size_t)k * NUM_BINS + bin];

    __shared__ float sums[4][64];
    sums[wave][lane] = s;
    __syncthreads();

    if (wave == 0) {
        float t = sums[0][lane] + sums[1][lane] + sums[2][lane] + sums[3][lane];
        float v = (bin < NUM_BINS) ? fabsf(t) : 0.0f;
        for (int off = 32; off > 0; off >>= 1)
            v += __shfl_down(v, off, 64);
        if (lane == 0) atomicAdd(out, v);
    }
}

extern "C" void kernel_launch(void* const* d_in, const int* in_sizes, int n_in,
                              void* d_out, int out_size, void* d_ws, size_t ws_size,
                              hipStream_t stream) {
    const float* od = (const float*)d_in[0];   // origin_density
    const int*   om = (const int*)d_in[1];     // origin_mask
    const float* pd = (const float*)d_in[2];   // pre_density
    const int*   nm = (const int*)d_in[3];     // new_mask
    float* out = (float*)d_out;
    float* partial = (float*)d_ws;
    const int n = in_sizes[0];

    int nblk = NBLK;
    size_t need = (size_t)nblk * NUM_BINS * sizeof(float);
    if (need > ws_size) {
        nblk = (int)(ws_size / (NUM_BINS * sizeof(float)));
        if (nblk < 1) nblk = 1;
    }

    hipMemsetAsync(d_out, 0, sizeof(float), stream);
    hist_kernel<<<nblk, BLOCK, 0, stream>>>(od, om, pd, nm, partial, n);
    reduce_kernel<<<(NUM_BINS + 63) / 64, 256, 0, stream>>>(partial, out, nblk);
}

// Round 3
// 242.903 us; speedup vs baseline: 1.3608x; 1.3608x over previous
//
#include <hip/hip_runtime.h>

#define NUM_BINS 1025
#define ROWS 1026              // bins + 1 dump row for dedup-redirected writes
#define GRID1 256              // one 131KB-LDS block per CU
#define SCALE 256.0f
#define INV_SCALE 0.00390625f  // 2^-8

// Batch-of-4 non-atomic i16 RMW with exact in-register dedupe.
// Guarantees the 4 live addresses are pairwise distinct (dups merged into the
// earliest, their slot redirected to the dump row), so read-4-then-write-4 is
// race-free within the lane; cross-batch ordering is preserved by may-alias
// semantics + the in-order DS pipe.
__device__ __forceinline__ void upd4(short* h, int lane,
                                     int4 b, int d0, int d1, int d2, int d3)
{
    const int DUMP = NUM_BINS * 64 + lane;
    const int a0 = b.x * 64 + lane;
    const bool m1  = (b.y == b.x);
    const int a1 = m1 ? DUMP : b.y * 64 + lane;
    d0 += m1 ? d1 : 0;
    const bool m20 = (b.z == b.x);
    const bool m21 = (b.z == b.y) && !m20;        // transitivity keeps targets live
    const int a2 = (m20 || m21) ? DUMP : b.z * 64 + lane;
    d0 += m20 ? d2 : 0;
    d1 += m21 ? d2 : 0;
    const bool m30 = (b.w == b.x);
    const bool m31 = (b.w == b.y) && !m30;
    const bool m32 = (b.w == b.z) && !(m30 || m31);
    const int a3 = (m30 || m31 || m32) ? DUMP : b.w * 64 + lane;
    d0 += m30 ? d3 : 0;
    d1 += m31 ? d3 : 0;
    d2 += m32 ? d3 : 0;
    const int t0 = h[a0]; const int t1 = h[a1];
    const int t2 = h[a2]; const int t3 = h[a3];
    h[a0] = (short)(t0 + d0);
    h[a1] = (short)(t1 + d1);
    h[a2] = (short)(t2 + d2);
    h[a3] = (short)(t3 + d3);
}

__global__ __launch_bounds__(64) void hist_kernel(
    const float* __restrict__ od, const int* __restrict__ om,
    const float* __restrict__ pd, const int* __restrict__ nm,
    int* __restrict__ partial, int n)
{
    extern __shared__ short h[];   // [ROWS][64] i16, column per lane
    const int lane = threadIdx.x;

    int* hw = (int*)h;
    #pragma unroll 4
    for (int i = lane; i < ROWS * 32; i += 64) hw[i] = 0;

    const int n4   = n >> 2;
    const int grid = (int)gridDim.x;
    const int qpb  = (n4 + grid - 1) / grid;
    const int start = (int)blockIdx.x * qpb;
    const int end   = min(n4, start + qpb);

    const float4* od4 = (const float4*)od;
    const int4*   om4 = (const int4*)om;
    const float4* pd4 = (const float4*)pd;
    const int4*   nm4 = (const int4*)nm;

    // depth-2 software prefetch
    float4 dA = {}, dB = {}; int4 mA = {}, mB = {};
    float4 eA = {}, eB = {}; int4 qA = {}, qB = {};
    const int iA = start + lane;
    const int iB = iA + 64;
    if (iA < end) { dA = od4[iA]; mA = om4[iA]; eA = pd4[iA]; qA = nm4[iA]; }
    if (iB < end) { dB = od4[iB]; mB = om4[iB]; eB = pd4[iB]; qB = nm4[iB]; }

    for (int i = iA; i < end; i += 64) {
        const int ip = i + 128;
        float4 dN = {}; int4 mN = {}; float4 eN = {}; int4 qN = {};
        if (ip < end) { dN = od4[ip]; mN = om4[ip]; eN = pd4[ip]; qN = nm4[ip]; }

        const int d0 = __float2int_rn(dA.x * SCALE);
        const int d1 = __float2int_rn(dA.y * SCALE);
        const int d2 = __float2int_rn(dA.z * SCALE);
        const int d3 = __float2int_rn(dA.w * SCALE);
        upd4(h, lane, mA, d0, d1, d2, d3);

        const int e0 = __float2int_rn(eA.x * -SCALE);
        const int e1 = __float2int_rn(eA.y * -SCALE);
        const int e2 = __float2int_rn(eA.z * -SCALE);
        const int e3 = __float2int_rn(eA.w * -SCALE);
        upd4(h, lane, qA, e0, e1, e2, e3);

        dA = dB; mA = mB; eA = eB; qA = qB;
        dB = dN; mB = mN; eB = eN; qB = qN;
    }

    // scalar tail (n % 4) — lane 0 of block 0, its own column, in-order DS
    if (blockIdx.x == 0 && lane == 0) {
        for (int k = n4 << 2; k < n; ++k) {
            const int b = om[k];
            h[b * 64] = (short)(h[b * 64] + __float2int_rn(od[k] * SCALE));
            const int c = nm[k];
            h[c * 64] = (short)(h[c * 64] + __float2int_rn(-pd[k] * SCALE));
        }
    }

    // flush: each lane sums 64 columns of its bins; rotated col -> 2-way banks
    for (int b = lane; b < NUM_BINS; b += 64) {
        int s = 0;
        #pragma unroll
        for (int j = 0; j < 64; ++j) {
            const int col = (lane + j) & 63;
            s += h[b * 64 + col];
        }
        partial[b * grid + (int)blockIdx.x] = s;   // [bin][block] for stage 2
    }
}

// Stage 2: one 64-lane block per bin; coalesced i32 reads, exact int sum,
// |.| * 2^-8, one atomic per bin.
__global__ __launch_bounds__(64) void reduce_kernel(
    const int* __restrict__ partial, float* __restrict__ out, int nblk)
{
    const int bin  = blockIdx.x;
    const int lane = threadIdx.x;
    int s = 0;
    for (int k = lane; k < nblk; k += 64)
        s += partial[bin * nblk + k];
    for (int off = 32; off > 0; off >>= 1)
        s += __shfl_down(s, off, 64);
    if (lane == 0)
        atomicAdd(out, fabsf((float)s) * INV_SCALE);
}

extern "C" void kernel_launch(void* const* d_in, const int* in_sizes, int n_in,
                              void* d_out, int out_size, void* d_ws, size_t ws_size,
                              hipStream_t stream) {
    const float* od = (const float*)d_in[0];   // origin_density
    const int*   om = (const int*)d_in[1];     // origin_mask
    const float* pd = (const float*)d_in[2];   // pre_density
    const int*   nm = (const int*)d_in[3];     // new_mask
    float* out   = (float*)d_out;
    int* partial = (int*)d_ws;                 // NUM_BINS * GRID1 * 4 = 1.05 MB
    const int n = in_sizes[0];

    const int shbytes = ROWS * 64 * (int)sizeof(short);   // 131,328 B
    hipFuncSetAttribute((const void*)hist_kernel,
                        hipFuncAttributeMaxDynamicSharedMemorySize, shbytes);

    hipMemsetAsync(d_out, 0, sizeof(float), stream);
    hist_kernel<<<GRID1, 64, shbytes, stream>>>(od, om, pd, nm, partial, n);
    reduce_kernel<<<NUM_BINS, 64, 0, stream>>>(partial, out, GRID1);
}

// Round 4
// 68.480 us; speedup vs baseline: 4.8268x; 3.5471x over previous
//
#include <hip/hip_runtime.h>

#define NUM_BINS 1025
#define NBLK 512
#define BLOCK 256
#define SCALEF 1024.0f
#define INV_SCALE 0.0009765625f   // 2^-10

// Stage 1: per-block signed i32 LDS histogram via integer DS atomics.
__global__ __launch_bounds__(BLOCK) void hist_kernel(
    const float* __restrict__ od, const int* __restrict__ om,
    const float* __restrict__ pd, const int* __restrict__ nm,
    int* __restrict__ partial, int n, int nblk)
{
    __shared__ int lh[NUM_BINS];
    const int tid = threadIdx.x;
    for (int b = tid; b < NUM_BINS; b += BLOCK) lh[b] = 0;
    __syncthreads();

    const int n4 = n >> 2;
    const float4* od4 = (const float4*)od;
    const int4*   om4 = (const int4*)om;
    const float4* pd4 = (const float4*)pd;
    const int4*   nm4 = (const int4*)nm;

    const int stride = gridDim.x * BLOCK;
    int i = blockIdx.x * BLOCK + tid;
    if (i < n4) {
        float4 d = od4[i]; int4 m = om4[i];
        float4 e = pd4[i]; int4 q = nm4[i];
        for (;;) {
            const int j = i + stride;
            const bool more = j < n4;
            float4 d2, e2; int4 m2, q2;
            if (more) { d2 = od4[j]; m2 = om4[j]; e2 = pd4[j]; q2 = nm4[j]; }
            atomicAdd(&lh[m.x],  __float2int_rn(d.x * SCALEF));
            atomicAdd(&lh[m.y],  __float2int_rn(d.y * SCALEF));
            atomicAdd(&lh[m.z],  __float2int_rn(d.z * SCALEF));
            atomicAdd(&lh[m.w],  __float2int_rn(d.w * SCALEF));
            atomicAdd(&lh[q.x], -__float2int_rn(e.x * SCALEF));
            atomicAdd(&lh[q.y], -__float2int_rn(e.y * SCALEF));
            atomicAdd(&lh[q.z], -__float2int_rn(e.z * SCALEF));
            atomicAdd(&lh[q.w], -__float2int_rn(e.w * SCALEF));
            if (!more) break;
            d = d2; m = m2; e = e2; q = q2; i = j;
        }
    }
    // scalar tail (n % 4) — empty for 4096x4096
    if (blockIdx.x == 0 && tid == 0) {
        for (int k = n4 << 2; k < n; ++k) {
            atomicAdd(&lh[om[k]],  __float2int_rn(od[k] * SCALEF));
            atomicAdd(&lh[nm[k]], -__float2int_rn(pd[k] * SCALEF));
        }
    }
    __syncthreads();

    // transposed flush: partial[bin][block] so stage 2 reads coalesced
    for (int b = tid; b < NUM_BINS; b += BLOCK)
        partial[b * nblk + (int)blockIdx.x] = lh[b];
}

// Stage 2: one 64-lane block per bin; coalesced i32 reads, exact int sum,
// |.| * 2^-10, one atomic per bin.
__global__ __launch_bounds__(64) void reduce_kernel(
    const int* __restrict__ partial, float* __restrict__ out, int nblk)
{
    const int bin  = blockIdx.x;
    const int lane = threadIdx.x;
    int s = 0;
    for (int k = lane; k < nblk; k += 64)
        s += partial[bin * nblk + k];
    for (int off = 32; off > 0; off >>= 1)
        s += __shfl_down(s, off, 64);
    if (lane == 0)
        atomicAdd(out, fabsf((float)s) * INV_SCALE);
}

extern "C" void kernel_launch(void* const* d_in, const int* in_sizes, int n_in,
                              void* d_out, int out_size, void* d_ws, size_t ws_size,
                              hipStream_t stream) {
    const float* od = (const float*)d_in[0];   // origin_density
    const int*   om = (const int*)d_in[1];     // origin_mask
    const float* pd = (const float*)d_in[2];   // pre_density
    const int*   nm = (const int*)d_in[3];     // new_mask
    float* out   = (float*)d_out;
    int* partial = (int*)d_ws;                 // NUM_BINS * NBLK * 4 = 2.1 MB
    const int n = in_sizes[0];

    int nblk = NBLK;
    size_t need = (size_t)NUM_BINS * nblk * sizeof(int);
    if (need > ws_size) {
        nblk = (int)(ws_size / (NUM_BINS * sizeof(int)));
        if (nblk < 1) nblk = 1;
    }

    hipMemsetAsync(d_out, 0, sizeof(float), stream);
    hist_kernel<<<nblk, BLOCK, 0, stream>>>(od, om, pd, nm, partial, n, nblk);
    reduce_kernel<<<NUM_BINS, 64, 0, stream>>>(partial, out, nblk);
}